// Round 17
// baseline (191.220 us; speedup 1.0000x reference)
//
#include <hip/hip_runtime.h>
#include <hip/hip_bf16.h>

// ---------------------------------------------------------------------------
// Problem constants (BATCH=1)
#define SEQ    2048
#define DM     2048
#define NH     16
#define DH     128
#define EPS    1e-5f
#define SCALE_INV 0.08838834764831845f   // 1/sqrt(128)
#define SC2LOG    0.12751744995f         // (1/sqrt(128)) * log2(e)

typedef unsigned short u16;
typedef u16  u16x4  __attribute__((ext_vector_type(4)));
typedef u16  u16x8  __attribute__((ext_vector_type(8)));
typedef unsigned u32x4 __attribute__((ext_vector_type(4)));
typedef __bf16 bf16x8 __attribute__((ext_vector_type(8)));
typedef float f32x4 __attribute__((ext_vector_type(4)));

__device__ __forceinline__ u16 f2bf(float f) {
    unsigned int u = __builtin_bit_cast(unsigned int, f);
    u += 0x7fffu + ((u >> 16) & 1u);      // RNE
    return (u16)(u >> 16);
}
__device__ __forceinline__ float bf2f(u16 v) {
    return __builtin_bit_cast(float, (unsigned)v << 16);
}
__device__ __forceinline__ bf16x8 as_bf(u16x8 v) { return __builtin_bit_cast(bf16x8, v); }

// async global->LDS, 16B per lane.  LDS dest must be wave-uniform base + lane*16.
__device__ __forceinline__ void gload16(const u16* g, u16* l) {
    __builtin_amdgcn_global_load_lds(
        (const __attribute__((address_space(1))) unsigned int*)g,
        (__attribute__((address_space(3))) unsigned int*)l, 16, 0, 0);
}

#define VMCNT(N) asm volatile("s_waitcnt vmcnt(" #N ")" ::: "memory")
#define LGKMCNT0 asm volatile("s_waitcnt lgkmcnt(0)" ::: "memory")
#define SCHEDBAR __builtin_amdgcn_sched_barrier(0)
#define BARRIER  __builtin_amdgcn_s_barrier()

// ---------------------------------------------------------------------------
// 1) fused prep: blocks 0..2047 = LayerNorm rows (+ rope row); blocks 2048+ =
//    weight transpose tiles (z<48: W{Q,K,V}; z>=48: WO).
__global__ __launch_bounds__(256) void prep_kernel(const float* __restrict__ x,
                                                   const float* __restrict__ WQ,
                                                   const float* __restrict__ WK,
                                                   const float* __restrict__ WV,
                                                   const float* __restrict__ WO,
                                                   u16* __restrict__ xn,
                                                   float2* __restrict__ rope,
                                                   u16* __restrict__ outW,
                                                   u16* __restrict__ outWO) {
    __shared__ union {
        struct { float ss[4], qq[4]; } ln;
        u16 tile[64][65];
    } sm;
    int bid = blockIdx.x;
    int t = threadIdx.x;
    if (bid < SEQ) {
        // ---- LayerNorm row + rope ----
        int row = bid;
        if (t < 64) {
            float freq = powf(10000.f, (float)t * (1.f / 64.f));
            float ang = (float)row / freq;
            rope[row * 64 + t] = make_float2(sinf(ang), cosf(ang));
        }
        const float* xr = x + (size_t)row * DM;
        float4 v0 = *(const float4*)(xr + t * 4);
        float4 v1 = *(const float4*)(xr + 1024 + t * 4);
        float s = v0.x + v0.y + v0.z + v0.w + v1.x + v1.y + v1.z + v1.w;
        float q = v0.x*v0.x + v0.y*v0.y + v0.z*v0.z + v0.w*v0.w
                + v1.x*v1.x + v1.y*v1.y + v1.z*v1.z + v1.w*v1.w;
        #pragma unroll
        for (int o = 32; o; o >>= 1) { s += __shfl_xor(s, o); q += __shfl_xor(q, o); }
        if ((t & 63) == 0) { sm.ln.ss[t >> 6] = s; sm.ln.qq[t >> 6] = q; }
        __syncthreads();
        s = sm.ln.ss[0] + sm.ln.ss[1] + sm.ln.ss[2] + sm.ln.ss[3];
        q = sm.ln.qq[0] + sm.ln.qq[1] + sm.ln.qq[2] + sm.ln.qq[3];
        float mean = s * (1.f / DM);
        float var  = q * (1.f / DM) - mean * mean;
        float rstd = rsqrtf(var + EPS);
        u16* orow = xn + (size_t)row * DM;
        u16x4 o0 = { f2bf((v0.x-mean)*rstd), f2bf((v0.y-mean)*rstd),
                     f2bf((v0.z-mean)*rstd), f2bf((v0.w-mean)*rstd) };
        u16x4 o1 = { f2bf((v1.x-mean)*rstd), f2bf((v1.y-mean)*rstd),
                     f2bf((v1.z-mean)*rstd), f2bf((v1.w-mean)*rstd) };
        *(u16x4*)(orow + t * 4) = o0;
        *(u16x4*)(orow + 1024 + t * 4) = o1;
    } else {
        // ---- weight transpose tile ----
        int tid = bid - SEQ;                   // 0..4095
        int bx = tid & 1, by = (tid >> 1) & 31, z = tid >> 6;
        const float* in;
        u16* o;
        int r0 = by * 64, c0;
        int inC, outC;
        if (z < 48) {
            int which = z >> 4, h = z & 15;
            in = ((which == 0) ? WQ : (which == 1) ? WK : WV) + (size_t)h * DM * DH;
            o  = outW + (size_t)z * DM * DH;
            c0 = bx * 64;
            inC = DH; outC = DM;
        } else {
            in = WO; o = outWO;
            c0 = ((z - 48) * 2 + bx) * 64;
            inC = DM; outC = DM;
        }
        #pragma unroll
        for (int it = 0; it < 4; ++it) {
            int idx = t + it * 256;
            int rr = idx >> 4, cc = (idx & 15) * 4;
            float4 v = *(const float4*)(in + (size_t)(r0 + rr) * inC + c0 + cc);
            sm.tile[rr][cc+0] = f2bf(v.x); sm.tile[rr][cc+1] = f2bf(v.y);
            sm.tile[rr][cc+2] = f2bf(v.z); sm.tile[rr][cc+3] = f2bf(v.w);
        }
        __syncthreads();
        #pragma unroll
        for (int it = 0; it < 4; ++it) {
            int idx = t + it * 256;
            int oc = idx >> 4, orr = (idx & 15) * 4;
            u16x4 w = { sm.tile[orr+0][oc], sm.tile[orr+1][oc],
                        sm.tile[orr+2][oc], sm.tile[orr+3][oc] };
            *(u16x4*)(o + (size_t)(c0 + oc) * outC + r0 + orr) = w;
        }
    }
}

// ---------------------------------------------------------------------------
// 4) QKV GEMM, 128x256 tile, BK=64, 8 waves (2x4), TRIPLE-buffered LDS (144 KB)
//    with counted vmcnt pipeline: loads issued 2 K-tiles ahead, VMCNT(6) leaves
//    next tile's loads in flight, ONE barrier per K-tile, no drain in loop.
//    Buffer safety: buf (kt+2)%3 staged at iter kt was last read at iter kt-1,
//    whose ds_reads retire at its lgkmcnt(0) before the barrier of iter kt.
//    Grid = 16x24 = 384 blocks (1/CU at 144 KB LDS + backfill).
__global__ __launch_bounds__(512, 1) void gemm_qkv(const u16* __restrict__ Xn,
                                                   const u16* __restrict__ Wt,
                                                   const float* __restrict__ bQ,
                                                   const float* __restrict__ bK,
                                                   const float* __restrict__ bV,
                                                   const float2* __restrict__ rope,
                                                   u16* __restrict__ qkv) {
    __shared__ u16 As[3][128 * 64], Bs[3][256 * 64];      // 48+96 = 144 KB
    int id = blockIdx.x;                                  // 0..383
    int swz = (id & 7) * 48 + (id >> 3);                  // bijective XCD swizzle
    int bx = swz & 15, by = swz >> 4;                     // 16 M-tiles x 24 N-tiles
    int m0 = bx * 128, n0 = by * 256;

    int t = threadIdx.x, lane = t & 63, wid = t >> 6;
    int wr = wid >> 2, wc = wid & 3;                      // 2 x 4 wave grid
    int cl = lane & 15, g = lane >> 4;

    auto stage = [&](int buf, int kt) {
        const u16* xa = Xn + (size_t)kt * 64;
        const u16* xb = Wt + (size_t)kt * 64;
        #pragma unroll
        for (int j = 0; j < 2; ++j) {                     // A: 128 rows -> 2 loads
            int idx = t + j * 512;
            int row = idx >> 3;
            int slotS = (idx & 7) ^ (row & 7);
            gload16(xa + (size_t)(m0 + row) * DM + slotS * 8, &As[buf][idx * 8]);
        }
        #pragma unroll
        for (int j = 0; j < 4; ++j) {                     // B: 256 rows -> 4 loads
            int idx = t + j * 512;
            int row = idx >> 3;
            int slotS = (idx & 7) ^ (row & 7);
            gload16(xb + (size_t)(n0 + row) * DM + slotS * 8, &Bs[buf][idx * 8]);
        }
    };

    f32x4 acc[4][4] = {};
    stage(0, 0);                                   // 6 loads in flight
    stage(1, 1);                                   // 12 in flight
    int buf = 0;

    for (int kt = 0; kt < 32; ++kt) {
        if (kt < 31) { VMCNT(6); } else { VMCNT(0); }   // tile kt landed; kt+1 in flight
        SCHEDBAR;
        BARRIER;                                   // all waves: buf ready
        SCHEDBAR;                                  // pin: nothing hoists above barrier

        bf16x8 af[4][2], bfr[4][2];
        #pragma unroll
        for (int mi = 0; mi < 4; ++mi)
            #pragma unroll
            for (int kk = 0; kk < 2; ++kk) {
                int row = wr * 64 + mi * 16 + cl;
                int s = (kk * 4 + g) ^ (row & 7);
                af[mi][kk] = as_bf(*(const u16x8*)&As[buf][row * 64 + s * 8]);
            }
        #pragma unroll
        for (int nj = 0; nj < 4; ++nj)
            #pragma unroll
            for (int kk = 0; kk < 2; ++kk) {
                int row = wc * 64 + nj * 16 + cl;
                int s = (kk * 4 + g) ^ (row & 7);
                bfr[nj][kk] = as_bf(*(const u16x8*)&Bs[buf][row * 64 + s * 8]);
            }
        if (kt + 2 < 32) {
            int nbuf = buf + 2; if (nbuf >= 3) nbuf -= 3;
            stage(nbuf, kt + 2);                   // issue 2 tiles ahead
        }
        __builtin_amdgcn_s_setprio(1);
        #pragma unroll
        for (int mi = 0; mi < 4; ++mi)
            #pragma unroll
            for (int nj = 0; nj < 4; ++nj)
                #pragma unroll
                for (int kk = 0; kk < 2; ++kk)
                    acc[mi][nj] = __builtin_amdgcn_mfma_f32_16x16x32_bf16(af[mi][kk], bfr[nj][kk], acc[mi][nj], 0, 0, 0);
        __builtin_amdgcn_s_setprio(0);
        LGKMCNT0;                                  // this wave's ds_reads of buf retired
        SCHEDBAR;
        buf = (buf + 1 == 3) ? 0 : buf + 1;
    }

    // epilogue: cols n0 + wc*64 + nj*16 + cl; 256-wide tile = exactly 2 heads
    #pragma unroll
    for (int mi = 0; mi < 4; ++mi)
        #pragma unroll
        for (int nj = 0; nj < 4; ++nj) {
            int eg = n0 + wc * 64 + nj * 16 + cl;       // global col in [0,6144)
            int which = eg >> 11;
            int h = (eg >> 7) & 15;
            int e = eg & 127;
            const float* bias = (which == 0) ? bQ : (which == 1) ? bK : bV;
            float bb = bias[h * DH + e];
            int p0 = m0 + wr * 64 + mi * 16 + g * 4;
            if (which == 2) {
                u16* vbase = qkv + 2ll * NH * SEQ * DH + (size_t)h * DH * SEQ;
                u16x4 o = { f2bf(acc[mi][nj][0] + bb), f2bf(acc[mi][nj][1] + bb),
                            f2bf(acc[mi][nj][2] + bb), f2bf(acc[mi][nj][3] + bb) };
                *(u16x4*)(vbase + (size_t)e * SEQ + p0) = o;
            } else {
                u16* outbase = qkv + ((size_t)which * 16 + h) * SEQ * DH;
                #pragma unroll
                for (int r = 0; r < 4; ++r) {
                    int pp = p0 + r;
                    float v = acc[mi][nj][r] + bb;
                    float pv = __shfl_xor(v, 1);
                    float2 sc2 = rope[pp * 64 + (e >> 1)];
                    v = (e & 1) ? (v * sc2.y + pv * sc2.x) : (v * sc2.y - pv * sc2.x);
                    outbase[(size_t)pp * DH + e] = f2bf(v);
                }
            }
        }
}

// ---------------------------------------------------------------------------
// part prefix for multi-chunk q-tiles (j>=8): Sigma_{jj=8..j-1} (jj/8+1)
__device__ __forceinline__ int part_prefix(int j) {
    return (j < 16) ? 2 * (j - 8) : (j < 24 ? 16 + 3 * (j - 16) : 40 + 4 * (j - 24));
}

// ---------------------------------------------------------------------------
// 5) causal flash attention with KV-split (chunks of <=8 KV-tiles).
//    grid (NH, 80): block = (h, j, c), biggest q-tiles first.
//    Swapped QK^T, per-lane scalar softmax, defer-max; P^T -> PV A-frag via
//    IN-REGISTER cvt_pk + 16-shfl transpose (no LDS round-trip).
__global__ __launch_bounds__(256) void flash_kernel(const u16* __restrict__ Qg,
                                                    const u16* __restrict__ Kg,
                                                    const u16* __restrict__ Vt,
                                                    u16* __restrict__ Zg,
                                                    u16* __restrict__ pO,
                                                    float2* __restrict__ ml) {
    __shared__ u16 kt[64 * 128];            // K tile, rows kv (256B), slot-swizzled
    __shared__ u16 vt[128 * 64];            // V^T tile, rows e (128B), slot-swizzled
    int h = blockIdx.x;
    int rem = blockIdx.y;
    int j = 31, c = 0;
    #pragma unroll 1
    for (int jj = 31; jj >= 0; --jj) {      // biggest first
        int ncj = (jj >> 3) + 1;
        if (rem < ncj) { j = jj; c = rem; break; }
        rem -= ncj;
    }
    int q0 = j * 64;
    int nc = (j >> 3) + 1;
    bool multi = (nc > 1);
    int kt0 = c * 8;
    int kt1 = min(j, c * 8 + 7);

    int t = threadIdx.x, lane = t & 63, w = t >> 6;
    int cl = lane & 15, g = lane >> 4;
    int qw0 = q0 + w * 16;
    const size_t hs = (size_t)h * SEQ;
    // shuffle sources for in-register P transpose
    int src0 = cl + ((g & 1) << 5);         // cl + 16*((g&1)*2)
    int src1 = src0 + 16;
    bool hi = ((g >> 1) & 1) != 0;

    bf16x8 qf[4];
    #pragma unroll
    for (int st = 0; st < 4; ++st)
        qf[st] = as_bf(*(const u16x8*)(Qg + (hs + qw0 + cl) * DH + st * 32 + g * 8));

    f32x4 acc[8] = {};
    float mrun = -3e38f, lsum = 0.f;

    u16x8 kreg[4], vreg[4];
    auto load_tile = [&](int kv0) {
        #pragma unroll
        for (int jj = 0; jj < 4; ++jj) {
            int idx = t + jj * 256;
            kreg[jj] = *(const u16x8*)(Kg + (hs + kv0 + (idx >> 4)) * DH + (idx & 15) * 8);
            vreg[jj] = *(const u16x8*)(Vt + ((size_t)h * DH + (idx >> 3)) * SEQ + kv0 + (idx & 7) * 8);
        }
    };
    auto store_tile = [&]() {
        #pragma unroll
        for (int jj = 0; jj < 4; ++jj) {
            int idx = t + jj * 256;
            int row = idx >> 4, slot = idx & 15;
            *(u16x8*)((char*)kt + row * 256 + ((slot ^ (row & 7)) * 16)) = kreg[jj];
            int e = idx >> 3, ch = idx & 7;
            *(u16x8*)((char*)vt + e * 128 + ((ch ^ (e & 7)) * 16)) = vreg[jj];
        }
    };

    int kvbeg = kt0 * 64, kvend = kt1 * 64;
    load_tile(kvbeg);
    store_tile();

    for (int kv0 = kvbeg; kv0 <= kvend; kv0 += 64) {
        __syncthreads();
        bool more = (kv0 + 64 <= kvend);
        if (more) load_tile(kv0 + 64);

        // S^T = K Q^T: col = q = cl, row = kv = cc*16 + g*4 + r
        f32x4 sc[4] = {};
        __builtin_amdgcn_s_setprio(1);
        #pragma unroll
        for (int st = 0; st < 4; ++st)
            #pragma unroll
            for (int cc = 0; cc < 4; ++cc) {
                int row = cc * 16 + cl;
                bf16x8 kf = as_bf(*(const u16x8*)((char*)kt + row * 256 + (((st * 4 + g) ^ (row & 7)) * 16)));
                sc[cc] = __builtin_amdgcn_mfma_f32_16x16x32_bf16(kf, qf[st], sc[cc], 0, 0, 0);
            }
        __builtin_amdgcn_s_setprio(0);

        bool needmask = (kv0 + 63 > qw0);
        int qrow = qw0 + cl;
        float pf[4][4];
        float tm = -3e38f;
        #pragma unroll
        for (int cc = 0; cc < 4; ++cc)
            #pragma unroll
            for (int r = 0; r < 4; ++r) {
                int kvq = kv0 + cc * 16 + g * 4 + r;
                float sval = sc[cc][r] * SC2LOG;
                if (needmask) sval = (kvq <= qrow) ? sval : -3e38f;
                pf[cc][r] = sval;
                tm = fmaxf(tm, sval);
            }
        tm = fmaxf(tm, __shfl_xor(tm, 16));
        tm = fmaxf(tm, __shfl_xor(tm, 32));

        if (!__all(tm <= mrun + 12.f)) {
            float mn = fmaxf(mrun, tm);
            float alpha = exp2f(mrun - mn);
            mrun = mn;
            lsum *= alpha;
            float aR[4];
            #pragma unroll
            for (int r = 0; r < 4; ++r) aR[r] = __shfl(alpha, g * 4 + r);
            #pragma unroll
            for (int n = 0; n < 8; ++n)
                #pragma unroll
                for (int r = 0; r < 4; ++r) acc[n][r] *= aR[r];
        }
        float rs = 0.f;
        #pragma unroll
        for (int cc = 0; cc < 4; ++cc)
            #pragma unroll
            for (int r = 0; r < 4; ++r) {
                float e2 = exp2f(pf[cc][r] - mrun);
                pf[cc][r] = e2;
                rs += e2;
            }
        rs += __shfl_xor(rs, 16);
        rs += __shfl_xor(rs, 32);
        lsum += rs;

        // ---- in-register P^T -> A-frag transpose ----
        unsigned U[4][2];
        #pragma unroll
        for (int cc = 0; cc < 4; ++cc) {
            asm("v_cvt_pk_bf16_f32 %0, %1, %2" : "=v"(U[cc][0]) : "v"(pf[cc][0]), "v"(pf[cc][1]));
            asm("v_cvt_pk_bf16_f32 %0, %1, %2" : "=v"(U[cc][1]) : "v"(pf[cc][2]), "v"(pf[cc][3]));
        }
        unsigned wv[2][4];
        #pragma unroll
        for (int ks = 0; ks < 2; ++ks)
            #pragma unroll
            for (int hh = 0; hh < 2; ++hh) {
                unsigned e0 = (unsigned)__shfl((int)U[2*ks][hh],   src0);
                unsigned e1 = (unsigned)__shfl((int)U[2*ks][hh],   src1);
                unsigned o0 = (unsigned)__shfl((int)U[2*ks+1][hh], src0);
                unsigned o1 = (unsigned)__shfl((int)U[2*ks+1][hh], src1);
                wv[ks][hh]     = hi ? o0 : e0;
                wv[ks][2 + hh] = hi ? o1 : e1;
            }
        bf16x8 pa[2];
        {
            u32x4 w0 = { wv[0][0], wv[0][1], wv[0][2], wv[0][3] };
            u32x4 w1 = { wv[1][0], wv[1][1], wv[1][2], wv[1][3] };
            pa[0] = __builtin_bit_cast(bf16x8, w0);
            pa[1] = __builtin_bit_cast(bf16x8, w1);
        }

        // PV: O rows q = g*4+r, cols e = n*16+cl
        __builtin_amdgcn_s_setprio(1);
        #pragma unroll
        for (int n = 0; n < 8; ++n)
            #pragma unroll
            for (int ks = 0; ks < 2; ++ks) {
                int e = n * 16 + cl;
                bf16x8 vf = as_bf(*(const u16x8*)((char*)vt + e * 128 + (((ks * 4 + g) ^ (e & 7)) * 16)));
                acc[n] = __builtin_amdgcn_mfma_f32_16x16x32_bf16(pa[ks], vf, acc[n], 0, 0, 0);
            }
        __builtin_amdgcn_s_setprio(0);

        if (!more) break;
        __syncthreads();
        store_tile();
    }

    if (multi) {
        int pidx = h * 72 + part_prefix(j) + c;
        if (lane < 16) ml[(size_t)pidx * 64 + w * 16 + cl] = make_float2(mrun, lsum);
        u16* po = pO + (size_t)pidx * (64 * 128);
        #pragma unroll
        for (int n = 0; n < 8; ++n)
            #pragma unroll
            for (int r = 0; r < 4; ++r)
                po[(w * 16 + g * 4 + r) * 128 + n * 16 + cl] = f2bf(acc[n][r]);
    } else {
        float inv = 1.0f / lsum;
        float invR[4];
        #pragma unroll
        for (int r = 0; r < 4; ++r) invR[r] = __shfl(inv, g * 4 + r);
        #pragma unroll
        for (int n = 0; n < 8; ++n)
            #pragma unroll
            for (int r = 0; r < 4; ++r) {
                int q = qw0 + g * 4 + r;
                Zg[(hs + q) * DH + n * 16 + cl] = f2bf(acc[n][r] * invR[r]);
            }
    }
}

// ---------------------------------------------------------------------------
// 5b) merge partial chunks: grid (NH, 24), j = blockIdx.y + 8
__global__ __launch_bounds__(256) void merge_kernel(const u16* __restrict__ pO,
                                                    const float2* __restrict__ ml,
                                                    u16* __restrict__ Zg) {
    int h = blockIdx.x;
    int j = blockIdx.y + 8;
    int nc = (j >> 3) + 1;                   // 2..4
    int pbase = h * 72 + part_prefix(j);
    int t = threadIdx.x;
    int row = t >> 2;                        // 0..63
    int c0 = (t & 3) * 32;

    float mv[4], lv[4];
    float M = -3e38f;
    #pragma unroll
    for (int i = 0; i < 4; ++i) {
        int ii = (i < nc) ? i : 0;
        float2 mli = ml[(size_t)(pbase + ii) * 64 + row];
        mv[i] = mli.x; lv[i] = mli.y;
        if (i < nc) M = fmaxf(M, mli.x);
    }
    float wgt[4];
    float L = 0.f;
    #pragma unroll
    for (int i = 0; i < 4; ++i) {
        wgt[i] = (i < nc) ? exp2f(mv[i] - M) : 0.f;
        L += wgt[i] * lv[i];
    }
    float invL = 1.f / L;

    #pragma unroll
    for (int ccc = 0; ccc < 32; ccc += 8) {
        float o[8] = {};
        #pragma unroll
        for (int i = 0; i < 4; ++i) {
            int ii = (i < nc) ? i : 0;
            u16x8 v = *(const u16x8*)(pO + ((size_t)(pbase + ii) * 64 + row) * 128 + c0 + ccc);
            #pragma unroll
            for (int k = 0; k < 8; ++k) o[k] += wgt[i] * bf2f(v[k]);
        }
        u16x8 zv;
        #pragma unroll
        for (int k = 0; k < 8; ++k) zv[k] = f2bf(o[k] * invL);
        *(u16x8*)(Zg + ((size_t)h * SEQ + j * 64 + row) * DH + c0 + ccc) = zv;
    }
}

// ---------------------------------------------------------------------------
// 6) output GEMM: 128x128 tile, BK=64, 4 waves, dbuf LDS, R7-style 1-barrier
//    schedule.  z[16][2048][128] x Wot[2048][2048] (B^T) + bO -> fp32 out
__global__ __launch_bounds__(256, 2) void gemm_out(const u16* __restrict__ Z,
                                                   const u16* __restrict__ Wot,
                                                   const float* __restrict__ bO,
                                                   float* __restrict__ out) {
    __shared__ u16 As[2][128 * 64], Bs[2][128 * 64];   // 64 KB
    int id = blockIdx.x;
    int swz = (id & 7) * 32 + (id >> 3);               // bijective XCD swizzle (256 blocks)
    int m0 = (swz & 15) * 128, n0 = (swz >> 4) * 128;
    int t = threadIdx.x, lane = t & 63, w = t >> 6;
    int wr = w >> 1, wc = w & 1;
    int cl = lane & 15, g = lane >> 4;

    auto stage = [&](int buf, int kt) {
        int k0 = kt * 64;
        int hh = k0 >> 7, e0 = k0 & 127;               // BK=64 never crosses a head
        #pragma unroll
        for (int j = 0; j < 4; ++j) {
            int idx = t + j * 256;                     // 0..1023
            int row = idx >> 3;                        // 0..127
            int slotS = (idx & 7) ^ (row & 7);         // inverse swizzle on SOURCE
            gload16(Z + ((size_t)hh * SEQ + m0 + row) * DH + e0 + slotS * 8, &As[buf][idx * 8]);
            gload16(Wot + (size_t)(n0 + row) * DM + k0 + slotS * 8, &Bs[buf][idx * 8]);
        }
    };

    f32x4 acc[4][4] = {};
    stage(0, 0);
    VMCNT(0);
    BARRIER;
    for (int kt = 0; kt < 32; ++kt) {
        int p = kt & 1;
        bool more = (kt + 1 < 32);
        bf16x8 af[4][2], bfr[4][2];
        #pragma unroll
        for (int i = 0; i < 4; ++i)
            #pragma unroll
            for (int kk = 0; kk < 2; ++kk) {
                int rowA = wr * 64 + i * 16 + cl;
                af[i][kk] = as_bf(*(const u16x8*)&As[p][rowA * 64 + (((kk * 4 + g) ^ (rowA & 7)) * 8)]);
                int rowB = wc * 64 + i * 16 + cl;
                bfr[i][kk] = as_bf(*(const u16x8*)&Bs[p][rowB * 64 + (((kk * 4 + g) ^ (rowB & 7)) * 8)]);
            }
        if (more) stage(p ^ 1, kt + 1);                // issue next tile early
        __builtin_amdgcn_s_setprio(1);
        #pragma unroll
        for (int i = 0; i < 4; ++i)
            #pragma unroll
            for (int j = 0; j < 4; ++j)
                #pragma unroll
                for (int kk = 0; kk < 2; ++kk)
                    acc[i][j] = __builtin_amdgcn_mfma_f32_16x16x32_bf16(af[i][kk], bfr[j][kk], acc[i][j], 0, 0, 0);
        __builtin_amdgcn_s_setprio(0);
        VMCNT(0);
        SCHEDBAR;
        BARRIER;
    }
    #pragma unroll
    for (int i = 0; i < 4; ++i)
        #pragma unroll
        for (int j = 0; j < 4; ++j) {
            int col = n0 + wc * 64 + j * 16 + cl;
            float bb = bO[col];
            #pragma unroll
            for (int r = 0; r < 4; ++r) {
                int p = m0 + wr * 64 + i * 16 + g * 4 + r;
                out[(size_t)p * DM + col] = acc[i][j][r] + bb;
            }
        }
}

// ---------------------------------------------------------------------------
extern "C" void kernel_launch(void* const* d_in, const int* in_sizes, int n_in,
                              void* d_out, int out_size, void* d_ws, size_t ws_size,
                              hipStream_t stream) {
    const float* resid = (const float*)d_in[0];
    const float* WQ = (const float*)d_in[1];
    const float* WK = (const float*)d_in[2];
    const float* WV = (const float*)d_in[3];
    const float* WO = (const float*)d_in[4];
    const float* bQ = (const float*)d_in[5];
    const float* bK = (const float*)d_in[6];
    const float* bV = (const float*)d_in[7];
    const float* bO = (const float*)d_in[8];
    float* out = (float*)d_out;
    char* ws = (char*)d_ws;

    float2* rope = (float2*)(ws);                        // 1 MB
    u16* xn   = (u16*)(ws + (1ll  << 20));               // 8 MB
    u16* Wt   = (u16*)(ws + (9ll  << 20));               // 24 MB  [3][16][128][2048]
    u16* Wot  = (u16*)(ws + (33ll << 20));               // 8 MB   [2048][2048]
    u16* qkv  = (u16*)(ws + (41ll << 20));               // 24 MB  [q][k][vT]
    u16* z    = (u16*)(ws + (65ll << 20));               // 8 MB   [16][2048][128]
    // flash partials OVERLAY rope/xn/Wt (dead after gemm_qkv; rewritten next call)
    u16* pO   = (u16*)(ws);                              // 18.9 MB (1152 x 64 x 128 bf16)
    float2* ml = (float2*)(ws + (20ll << 20));           // 0.6 MB

    prep_kernel<<<SEQ + 4096, 256, 0, stream>>>(resid, WQ, WK, WV, WO, xn, rope, Wt, Wot);

    gemm_qkv<<<384, 512, 0, stream>>>(xn, Wt, bQ, bK, bV, rope, qkv);

    const u16* Qg = qkv;
    const u16* Kg = qkv + 1ll * NH * SEQ * DH;
    const u16* Vt = qkv + 2ll * NH * SEQ * DH;
    flash_kernel<<<dim3(NH, 80), 256, 0, stream>>>(Qg, Kg, Vt, z, pO, ml);
    merge_kernel<<<dim3(NH, 24), 256, 0, stream>>>(pO, ml, z);

    gemm_out<<<256, 256, 0, stream>>>(z, Wot, bO, out);
}

// Round 18
// 175.487 us; speedup vs baseline: 1.0897x; 1.0897x over previous
//
#include <hip/hip_runtime.h>
#include <hip/hip_bf16.h>

// ---------------------------------------------------------------------------
// Problem constants (BATCH=1)
#define SEQ    2048
#define DM     2048
#define NH     16
#define DH     128
#define EPS    1e-5f
#define SCALE_INV 0.08838834764831845f   // 1/sqrt(128)
#define SC2LOG    0.12751744995f         // (1/sqrt(128)) * log2(e)

typedef unsigned short u16;
typedef u16  u16x4  __attribute__((ext_vector_type(4)));
typedef u16  u16x8  __attribute__((ext_vector_type(8)));
typedef unsigned u32x4 __attribute__((ext_vector_type(4)));
typedef __bf16 bf16x8 __attribute__((ext_vector_type(8)));
typedef float f32x4 __attribute__((ext_vector_type(4)));

__device__ __forceinline__ u16 f2bf(float f) {
    unsigned int u = __builtin_bit_cast(unsigned int, f);
    u += 0x7fffu + ((u >> 16) & 1u);      // RNE
    return (u16)(u >> 16);
}
__device__ __forceinline__ float bf2f(u16 v) {
    return __builtin_bit_cast(float, (unsigned)v << 16);
}
__device__ __forceinline__ bf16x8 as_bf(u16x8 v) { return __builtin_bit_cast(bf16x8, v); }

// async global->LDS, 16B per lane.  LDS dest must be wave-uniform base + lane*16.
__device__ __forceinline__ void gload16(const u16* g, u16* l) {
    __builtin_amdgcn_global_load_lds(
        (const __attribute__((address_space(1))) unsigned int*)g,
        (__attribute__((address_space(3))) unsigned int*)l, 16, 0, 0);
}

#define VMCNT(N) asm volatile("s_waitcnt vmcnt(" #N ")" ::: "memory")
#define LGKMCNT0 asm volatile("s_waitcnt lgkmcnt(0)" ::: "memory")
#define SCHEDBAR __builtin_amdgcn_sched_barrier(0)
#define BARRIER  __builtin_amdgcn_s_barrier()

// ---------------------------------------------------------------------------
// 1) fused prep: blocks 0..2047 = LayerNorm rows (+ rope row); blocks 2048+ =
//    weight transpose tiles (z<48: W{Q,K,V}; z>=48: WO).
__global__ __launch_bounds__(256) void prep_kernel(const float* __restrict__ x,
                                                   const float* __restrict__ WQ,
                                                   const float* __restrict__ WK,
                                                   const float* __restrict__ WV,
                                                   const float* __restrict__ WO,
                                                   u16* __restrict__ xn,
                                                   float2* __restrict__ rope,
                                                   u16* __restrict__ outW,
                                                   u16* __restrict__ outWO) {
    __shared__ union {
        struct { float ss[4], qq[4]; } ln;
        u16 tile[64][65];
    } sm;
    int bid = blockIdx.x;
    int t = threadIdx.x;
    if (bid < SEQ) {
        // ---- LayerNorm row + rope ----
        int row = bid;
        if (t < 64) {
            float freq = powf(10000.f, (float)t * (1.f / 64.f));
            float ang = (float)row / freq;
            rope[row * 64 + t] = make_float2(sinf(ang), cosf(ang));
        }
        const float* xr = x + (size_t)row * DM;
        float4 v0 = *(const float4*)(xr + t * 4);
        float4 v1 = *(const float4*)(xr + 1024 + t * 4);
        float s = v0.x + v0.y + v0.z + v0.w + v1.x + v1.y + v1.z + v1.w;
        float q = v0.x*v0.x + v0.y*v0.y + v0.z*v0.z + v0.w*v0.w
                + v1.x*v1.x + v1.y*v1.y + v1.z*v1.z + v1.w*v1.w;
        #pragma unroll
        for (int o = 32; o; o >>= 1) { s += __shfl_xor(s, o); q += __shfl_xor(q, o); }
        if ((t & 63) == 0) { sm.ln.ss[t >> 6] = s; sm.ln.qq[t >> 6] = q; }
        __syncthreads();
        s = sm.ln.ss[0] + sm.ln.ss[1] + sm.ln.ss[2] + sm.ln.ss[3];
        q = sm.ln.qq[0] + sm.ln.qq[1] + sm.ln.qq[2] + sm.ln.qq[3];
        float mean = s * (1.f / DM);
        float var  = q * (1.f / DM) - mean * mean;
        float rstd = rsqrtf(var + EPS);
        u16* orow = xn + (size_t)row * DM;
        u16x4 o0 = { f2bf((v0.x-mean)*rstd), f2bf((v0.y-mean)*rstd),
                     f2bf((v0.z-mean)*rstd), f2bf((v0.w-mean)*rstd) };
        u16x4 o1 = { f2bf((v1.x-mean)*rstd), f2bf((v1.y-mean)*rstd),
                     f2bf((v1.z-mean)*rstd), f2bf((v1.w-mean)*rstd) };
        *(u16x4*)(orow + t * 4) = o0;
        *(u16x4*)(orow + 1024 + t * 4) = o1;
    } else {
        // ---- weight transpose tile ----
        int tid = bid - SEQ;                   // 0..4095
        int bx = tid & 1, by = (tid >> 1) & 31, z = tid >> 6;
        const float* in;
        u16* o;
        int r0 = by * 64, c0;
        int inC, outC;
        if (z < 48) {
            int which = z >> 4, h = z & 15;
            in = ((which == 0) ? WQ : (which == 1) ? WK : WV) + (size_t)h * DM * DH;
            o  = outW + (size_t)z * DM * DH;
            c0 = bx * 64;
            inC = DH; outC = DM;
        } else {
            in = WO; o = outWO;
            c0 = ((z - 48) * 2 + bx) * 64;
            inC = DM; outC = DM;
        }
        #pragma unroll
        for (int it = 0; it < 4; ++it) {
            int idx = t + it * 256;
            int rr = idx >> 4, cc = (idx & 15) * 4;
            float4 v = *(const float4*)(in + (size_t)(r0 + rr) * inC + c0 + cc);
            sm.tile[rr][cc+0] = f2bf(v.x); sm.tile[rr][cc+1] = f2bf(v.y);
            sm.tile[rr][cc+2] = f2bf(v.z); sm.tile[rr][cc+3] = f2bf(v.w);
        }
        __syncthreads();
        #pragma unroll
        for (int it = 0; it < 4; ++it) {
            int idx = t + it * 256;
            int oc = idx >> 4, orr = (idx & 15) * 4;
            u16x4 w = { sm.tile[orr+0][oc], sm.tile[orr+1][oc],
                        sm.tile[orr+2][oc], sm.tile[orr+3][oc] };
            *(u16x4*)(o + (size_t)(c0 + oc) * outC + r0 + orr) = w;
        }
    }
}

// ---------------------------------------------------------------------------
// 4) QKV GEMM, 256x192 tile, BK=64, 8 waves (2x4), dbuf LDS (112 KB).
//    Grid = 8x32 = 256 blocks = 1/CU (100% CU coverage).
//    R7-proven schedule: frag reads -> stage(next) mid -> MFMA -> drain -> 1 barrier.
__global__ __launch_bounds__(512, 2) void gemm_qkv(const u16* __restrict__ Xn,
                                                   const u16* __restrict__ Wt,
                                                   const float* __restrict__ bQ,
                                                   const float* __restrict__ bK,
                                                   const float* __restrict__ bV,
                                                   const float2* __restrict__ rope,
                                                   u16* __restrict__ qkv) {
    __shared__ u16 As[2][256 * 64], Bs[2][192 * 64];      // 112 KB total
    int id = blockIdx.x;                                  // 0..255
    int swz = (id & 7) * 32 + (id >> 3);                  // bijective XCD swizzle
    int bx = swz & 7, by = swz >> 3;                      // 8 M-tiles x 32 N-tiles
    int m0 = bx * 256, n0 = by * 192;

    int t = threadIdx.x, lane = t & 63, wid = t >> 6;
    int wr = wid >> 2, wc = wid & 3;                      // 2 x 4 wave grid
    int cl = lane & 15, g = lane >> 4;

    auto stage = [&](int buf, int kt) {
        const u16* xa = Xn + (size_t)kt * 64;
        const u16* xb = Wt + (size_t)kt * 64;
        #pragma unroll
        for (int j = 0; j < 4; ++j) {                     // A: 256 rows
            int idx = t + j * 512;
            int row = idx >> 3;
            int slotS = (idx & 7) ^ (row & 7);
            gload16(xa + (size_t)(m0 + row) * DM + slotS * 8, &As[buf][idx * 8]);
        }
        #pragma unroll
        for (int j = 0; j < 3; ++j) {                     // B: 192 rows
            int idx = t + j * 512;
            int row = idx >> 3;
            int slotS = (idx & 7) ^ (row & 7);
            gload16(xb + (size_t)(n0 + row) * DM + slotS * 8, &Bs[buf][idx * 8]);
        }
    };

    f32x4 acc[8][3] = {};
    stage(0, 0);
    VMCNT(0);
    BARRIER;

    for (int kt = 0; kt < 32; ++kt) {
        int p = kt & 1;
        bool more = (kt + 1 < 32);
        bf16x8 bfr[3][2], af[4][2];
        #pragma unroll
        for (int nj = 0; nj < 3; ++nj)
            #pragma unroll
            for (int kk = 0; kk < 2; ++kk) {
                int row = wc * 48 + nj * 16 + cl;
                int s = (kk * 4 + g) ^ (row & 7);
                bfr[nj][kk] = as_bf(*(const u16x8*)&Bs[p][row * 64 + s * 8]);
            }
        #pragma unroll
        for (int mi = 0; mi < 4; ++mi)
            #pragma unroll
            for (int kk = 0; kk < 2; ++kk) {
                int row = wr * 128 + mi * 16 + cl;
                int s = (kk * 4 + g) ^ (row & 7);
                af[mi][kk] = as_bf(*(const u16x8*)&As[p][row * 64 + s * 8]);
            }
        if (more) stage(p ^ 1, kt + 1);            // issue next tile early
        __builtin_amdgcn_s_setprio(1);
        #pragma unroll
        for (int mi = 0; mi < 4; ++mi)
            #pragma unroll
            for (int nj = 0; nj < 3; ++nj)
                #pragma unroll
                for (int kk = 0; kk < 2; ++kk)
                    acc[mi][nj] = __builtin_amdgcn_mfma_f32_16x16x32_bf16(af[mi][kk], bfr[nj][kk], acc[mi][nj], 0, 0, 0);
        __builtin_amdgcn_s_setprio(0);
        #pragma unroll
        for (int mi = 0; mi < 4; ++mi)
            #pragma unroll
            for (int kk = 0; kk < 2; ++kk) {
                int row = wr * 128 + 64 + mi * 16 + cl;
                int s = (kk * 4 + g) ^ (row & 7);
                af[mi][kk] = as_bf(*(const u16x8*)&As[p][row * 64 + s * 8]);
            }
        __builtin_amdgcn_s_setprio(1);
        #pragma unroll
        for (int mi = 0; mi < 4; ++mi)
            #pragma unroll
            for (int nj = 0; nj < 3; ++nj)
                #pragma unroll
                for (int kk = 0; kk < 2; ++kk)
                    acc[4 + mi][nj] = __builtin_amdgcn_mfma_f32_16x16x32_bf16(af[mi][kk], bfr[nj][kk], acc[4 + mi][nj], 0, 0, 0);
        __builtin_amdgcn_s_setprio(0);
        VMCNT(0);                                  // drain (stage issued pre-MFMA: latency mostly hidden)
        SCHEDBAR;
        BARRIER;                                   // buf p free; buf p^1 ready
    }

    // epilogue: each 16-wide frag is 16-aligned -> never crosses head/which bounds
    #pragma unroll
    for (int i = 0; i < 8; ++i)
        #pragma unroll
        for (int nj = 0; nj < 3; ++nj) {
            int eg = n0 + wc * 48 + nj * 16 + cl;       // global col in [0,6144)
            int which = eg >> 11;
            int h = (eg >> 7) & 15;
            int e = eg & 127;
            const float* bias = (which == 0) ? bQ : (which == 1) ? bK : bV;
            float bb = bias[h * DH + e];
            int p0 = m0 + wr * 128 + i * 16 + g * 4;
            if (which == 2) {
                u16* vbase = qkv + 2ll * NH * SEQ * DH + (size_t)h * DH * SEQ;
                u16x4 o = { f2bf(acc[i][nj][0] + bb), f2bf(acc[i][nj][1] + bb),
                            f2bf(acc[i][nj][2] + bb), f2bf(acc[i][nj][3] + bb) };
                *(u16x4*)(vbase + (size_t)e * SEQ + p0) = o;
            } else {
                u16* outbase = qkv + ((size_t)which * 16 + h) * SEQ * DH;
                #pragma unroll
                for (int r = 0; r < 4; ++r) {
                    int pp = p0 + r;
                    float v = acc[i][nj][r] + bb;
                    float pv = __shfl_xor(v, 1);
                    float2 sc2 = rope[pp * 64 + (e >> 1)];
                    v = (e & 1) ? (v * sc2.y + pv * sc2.x) : (v * sc2.y - pv * sc2.x);
                    outbase[(size_t)pp * DH + e] = f2bf(v);
                }
            }
        }
}

// ---------------------------------------------------------------------------
// part prefix for multi-chunk q-tiles (j>=8): Sigma_{jj=8..j-1} (jj/8+1)
__device__ __forceinline__ int part_prefix(int j) {
    return (j < 16) ? 2 * (j - 8) : (j < 24 ? 16 + 3 * (j - 16) : 40 + 4 * (j - 24));
}

// ---------------------------------------------------------------------------
// 5) causal flash attention with KV-split (chunks of <=8 KV-tiles).
//    grid (NH, 80): block = (h, j, c), biggest q-tiles first.
//    Swapped QK^T, per-lane scalar softmax, defer-max; P^T -> PV A-frag via
//    IN-REGISTER cvt_pk + 16-shfl transpose (no LDS round-trip).
__global__ __launch_bounds__(256) void flash_kernel(const u16* __restrict__ Qg,
                                                    const u16* __restrict__ Kg,
                                                    const u16* __restrict__ Vt,
                                                    u16* __restrict__ Zg,
                                                    u16* __restrict__ pO,
                                                    float2* __restrict__ ml) {
    __shared__ u16 kt[64 * 128];            // K tile, rows kv (256B), slot-swizzled
    __shared__ u16 vt[128 * 64];            // V^T tile, rows e (128B), slot-swizzled
    int h = blockIdx.x;
    int rem = blockIdx.y;
    int j = 31, c = 0;
    #pragma unroll 1
    for (int jj = 31; jj >= 0; --jj) {      // biggest first
        int ncj = (jj >> 3) + 1;
        if (rem < ncj) { j = jj; c = rem; break; }
        rem -= ncj;
    }
    int q0 = j * 64;
    int nc = (j >> 3) + 1;
    bool multi = (nc > 1);
    int kt0 = c * 8;
    int kt1 = min(j, c * 8 + 7);

    int t = threadIdx.x, lane = t & 63, w = t >> 6;
    int cl = lane & 15, g = lane >> 4;
    int qw0 = q0 + w * 16;
    const size_t hs = (size_t)h * SEQ;
    // shuffle sources for in-register P transpose
    int src0 = cl + ((g & 1) << 5);         // cl + 16*((g&1)*2)
    int src1 = src0 + 16;
    bool hi = ((g >> 1) & 1) != 0;

    bf16x8 qf[4];
    #pragma unroll
    for (int st = 0; st < 4; ++st)
        qf[st] = as_bf(*(const u16x8*)(Qg + (hs + qw0 + cl) * DH + st * 32 + g * 8));

    f32x4 acc[8] = {};
    float mrun = -3e38f, lsum = 0.f;

    u16x8 kreg[4], vreg[4];
    auto load_tile = [&](int kv0) {
        #pragma unroll
        for (int jj = 0; jj < 4; ++jj) {
            int idx = t + jj * 256;
            kreg[jj] = *(const u16x8*)(Kg + (hs + kv0 + (idx >> 4)) * DH + (idx & 15) * 8);
            vreg[jj] = *(const u16x8*)(Vt + ((size_t)h * DH + (idx >> 3)) * SEQ + kv0 + (idx & 7) * 8);
        }
    };
    auto store_tile = [&]() {
        #pragma unroll
        for (int jj = 0; jj < 4; ++jj) {
            int idx = t + jj * 256;
            int row = idx >> 4, slot = idx & 15;
            *(u16x8*)((char*)kt + row * 256 + ((slot ^ (row & 7)) * 16)) = kreg[jj];
            int e = idx >> 3, ch = idx & 7;
            *(u16x8*)((char*)vt + e * 128 + ((ch ^ (e & 7)) * 16)) = vreg[jj];
        }
    };

    int kvbeg = kt0 * 64, kvend = kt1 * 64;
    load_tile(kvbeg);
    store_tile();

    for (int kv0 = kvbeg; kv0 <= kvend; kv0 += 64) {
        __syncthreads();
        bool more = (kv0 + 64 <= kvend);
        if (more) load_tile(kv0 + 64);

        // S^T = K Q^T: col = q = cl, row = kv = cc*16 + g*4 + r
        f32x4 sc[4] = {};
        __builtin_amdgcn_s_setprio(1);
        #pragma unroll
        for (int st = 0; st < 4; ++st)
            #pragma unroll
            for (int cc = 0; cc < 4; ++cc) {
                int row = cc * 16 + cl;
                bf16x8 kf = as_bf(*(const u16x8*)((char*)kt + row * 256 + (((st * 4 + g) ^ (row & 7)) * 16)));
                sc[cc] = __builtin_amdgcn_mfma_f32_16x16x32_bf16(kf, qf[st], sc[cc], 0, 0, 0);
            }
        __builtin_amdgcn_s_setprio(0);

        bool needmask = (kv0 + 63 > qw0);
        int qrow = qw0 + cl;
        float pf[4][4];
        float tm = -3e38f;
        #pragma unroll
        for (int cc = 0; cc < 4; ++cc)
            #pragma unroll
            for (int r = 0; r < 4; ++r) {
                int kvq = kv0 + cc * 16 + g * 4 + r;
                float sval = sc[cc][r] * SC2LOG;
                if (needmask) sval = (kvq <= qrow) ? sval : -3e38f;
                pf[cc][r] = sval;
                tm = fmaxf(tm, sval);
            }
        tm = fmaxf(tm, __shfl_xor(tm, 16));
        tm = fmaxf(tm, __shfl_xor(tm, 32));

        if (!__all(tm <= mrun + 12.f)) {
            float mn = fmaxf(mrun, tm);
            float alpha = exp2f(mrun - mn);
            mrun = mn;
            lsum *= alpha;
            float aR[4];
            #pragma unroll
            for (int r = 0; r < 4; ++r) aR[r] = __shfl(alpha, g * 4 + r);
            #pragma unroll
            for (int n = 0; n < 8; ++n)
                #pragma unroll
                for (int r = 0; r < 4; ++r) acc[n][r] *= aR[r];
        }
        float rs = 0.f;
        #pragma unroll
        for (int cc = 0; cc < 4; ++cc)
            #pragma unroll
            for (int r = 0; r < 4; ++r) {
                float e2 = exp2f(pf[cc][r] - mrun);
                pf[cc][r] = e2;
                rs += e2;
            }
        rs += __shfl_xor(rs, 16);
        rs += __shfl_xor(rs, 32);
        lsum += rs;

        // ---- in-register P^T -> A-frag transpose ----
        unsigned U[4][2];
        #pragma unroll
        for (int cc = 0; cc < 4; ++cc) {
            asm("v_cvt_pk_bf16_f32 %0, %1, %2" : "=v"(U[cc][0]) : "v"(pf[cc][0]), "v"(pf[cc][1]));
            asm("v_cvt_pk_bf16_f32 %0, %1, %2" : "=v"(U[cc][1]) : "v"(pf[cc][2]), "v"(pf[cc][3]));
        }
        unsigned wv[2][4];
        #pragma unroll
        for (int ks = 0; ks < 2; ++ks)
            #pragma unroll
            for (int hh = 0; hh < 2; ++hh) {
                unsigned e0 = (unsigned)__shfl((int)U[2*ks][hh],   src0);
                unsigned e1 = (unsigned)__shfl((int)U[2*ks][hh],   src1);
                unsigned o0 = (unsigned)__shfl((int)U[2*ks+1][hh], src0);
                unsigned o1 = (unsigned)__shfl((int)U[2*ks+1][hh], src1);
                wv[ks][hh]     = hi ? o0 : e0;
                wv[ks][2 + hh] = hi ? o1 : e1;
            }
        bf16x8 pa[2];
        {
            u32x4 w0 = { wv[0][0], wv[0][1], wv[0][2], wv[0][3] };
            u32x4 w1 = { wv[1][0], wv[1][1], wv[1][2], wv[1][3] };
            pa[0] = __builtin_bit_cast(bf16x8, w0);
            pa[1] = __builtin_bit_cast(bf16x8, w1);
        }

        // PV: O rows q = g*4+r, cols e = n*16+cl
        __builtin_amdgcn_s_setprio(1);
        #pragma unroll
        for (int n = 0; n < 8; ++n)
            #pragma unroll
            for (int ks = 0; ks < 2; ++ks) {
                int e = n * 16 + cl;
                bf16x8 vf = as_bf(*(const u16x8*)((char*)vt + e * 128 + (((ks * 4 + g) ^ (e & 7)) * 16)));
                acc[n] = __builtin_amdgcn_mfma_f32_16x16x32_bf16(pa[ks], vf, acc[n], 0, 0, 0);
            }
        __builtin_amdgcn_s_setprio(0);

        if (!more) break;
        __syncthreads();
        store_tile();
    }

    if (multi) {
        int pidx = h * 72 + part_prefix(j) + c;
        if (lane < 16) ml[(size_t)pidx * 64 + w * 16 + cl] = make_float2(mrun, lsum);
        u16* po = pO + (size_t)pidx * (64 * 128);
        #pragma unroll
        for (int n = 0; n < 8; ++n)
            #pragma unroll
            for (int r = 0; r < 4; ++r)
                po[(w * 16 + g * 4 + r) * 128 + n * 16 + cl] = f2bf(acc[n][r]);
    } else {
        float inv = 1.0f / lsum;
        float invR[4];
        #pragma unroll
        for (int r = 0; r < 4; ++r) invR[r] = __shfl(inv, g * 4 + r);
        #pragma unroll
        for (int n = 0; n < 8; ++n)
            #pragma unroll
            for (int r = 0; r < 4; ++r) {
                int q = qw0 + g * 4 + r;
                Zg[(hs + q) * DH + n * 16 + cl] = f2bf(acc[n][r] * invR[r]);
            }
    }
}

// ---------------------------------------------------------------------------
// 5b) merge partial chunks: grid (NH, 24), j = blockIdx.y + 8
__global__ __launch_bounds__(256) void merge_kernel(const u16* __restrict__ pO,
                                                    const float2* __restrict__ ml,
                                                    u16* __restrict__ Zg) {
    int h = blockIdx.x;
    int j = blockIdx.y + 8;
    int nc = (j >> 3) + 1;                   // 2..4
    int pbase = h * 72 + part_prefix(j);
    int t = threadIdx.x;
    int row = t >> 2;                        // 0..63
    int c0 = (t & 3) * 32;

    float mv[4], lv[4];
    float M = -3e38f;
    #pragma unroll
    for (int i = 0; i < 4; ++i) {
        int ii = (i < nc) ? i : 0;
        float2 mli = ml[(size_t)(pbase + ii) * 64 + row];
        mv[i] = mli.x; lv[i] = mli.y;
        if (i < nc) M = fmaxf(M, mli.x);
    }
    float wgt[4];
    float L = 0.f;
    #pragma unroll
    for (int i = 0; i < 4; ++i) {
        wgt[i] = (i < nc) ? exp2f(mv[i] - M) : 0.f;
        L += wgt[i] * lv[i];
    }
    float invL = 1.f / L;

    #pragma unroll
    for (int ccc = 0; ccc < 32; ccc += 8) {
        float o[8] = {};
        #pragma unroll
        for (int i = 0; i < 4; ++i) {
            int ii = (i < nc) ? i : 0;
            u16x8 v = *(const u16x8*)(pO + ((size_t)(pbase + ii) * 64 + row) * 128 + c0 + ccc);
            #pragma unroll
            for (int k = 0; k < 8; ++k) o[k] += wgt[i] * bf2f(v[k]);
        }
        u16x8 zv;
        #pragma unroll
        for (int k = 0; k < 8; ++k) zv[k] = f2bf(o[k] * invL);
        *(u16x8*)(Zg + ((size_t)h * SEQ + j * 64 + row) * DH + c0 + ccc) = zv;
    }
}

// ---------------------------------------------------------------------------
// 6) output GEMM: 128x128 tile, BK=64, 4 waves, dbuf LDS, R7-style 1-barrier
//    schedule.  z[16][2048][128] x Wot[2048][2048] (B^T) + bO -> fp32 out
__global__ __launch_bounds__(256, 2) void gemm_out(const u16* __restrict__ Z,
                                                   const u16* __restrict__ Wot,
                                                   const float* __restrict__ bO,
                                                   float* __restrict__ out) {
    __shared__ u16 As[2][128 * 64], Bs[2][128 * 64];   // 64 KB
    int id = blockIdx.x;
    int swz = (id & 7) * 32 + (id >> 3);               // bijective XCD swizzle (256 blocks)
    int m0 = (swz & 15) * 128, n0 = (swz >> 4) * 128;
    int t = threadIdx.x, lane = t & 63, w = t >> 6;
    int wr = w >> 1, wc = w & 1;
    int cl = lane & 15, g = lane >> 4;

    auto stage = [&](int buf, int kt) {
        int k0 = kt * 64;
        int hh = k0 >> 7, e0 = k0 & 127;               // BK=64 never crosses a head
        #pragma unroll
        for (int j = 0; j < 4; ++j) {
            int idx = t + j * 256;                     // 0..1023
            int row = idx >> 3;                        // 0..127
            int slotS = (idx & 7) ^ (row & 7);         // inverse swizzle on SOURCE
            gload16(Z + ((size_t)hh * SEQ + m0 + row) * DH + e0 + slotS * 8, &As[buf][idx * 8]);
            gload16(Wot + (size_t)(n0 + row) * DM + k0 + slotS * 8, &Bs[buf][idx * 8]);
        }
    };

    f32x4 acc[4][4] = {};
    stage(0, 0);
    VMCNT(0);
    BARRIER;
    for (int kt = 0; kt < 32; ++kt) {
        int p = kt & 1;
        bool more = (kt + 1 < 32);
        bf16x8 af[4][2], bfr[4][2];
        #pragma unroll
        for (int i = 0; i < 4; ++i)
            #pragma unroll
            for (int kk = 0; kk < 2; ++kk) {
                int rowA = wr * 64 + i * 16 + cl;
                af[i][kk] = as_bf(*(const u16x8*)&As[p][rowA * 64 + (((kk * 4 + g) ^ (rowA & 7)) * 8)]);
                int rowB = wc * 64 + i * 16 + cl;
                bfr[i][kk] = as_bf(*(const u16x8*)&Bs[p][rowB * 64 + (((kk * 4 + g) ^ (rowB & 7)) * 8)]);
            }
        if (more) stage(p ^ 1, kt + 1);                // issue next tile early
        __builtin_amdgcn_s_setprio(1);
        #pragma unroll
        for (int i = 0; i < 4; ++i)
            #pragma unroll
            for (int j = 0; j < 4; ++j)
                #pragma unroll
                for (int kk = 0; kk < 2; ++kk)
                    acc[i][j] = __builtin_amdgcn_mfma_f32_16x16x32_bf16(af[i][kk], bfr[j][kk], acc[i][j], 0, 0, 0);
        __builtin_amdgcn_s_setprio(0);
        VMCNT(0);
        SCHEDBAR;
        BARRIER;
    }
    #pragma unroll
    for (int i = 0; i < 4; ++i)
        #pragma unroll
        for (int j = 0; j < 4; ++j) {
            int col = n0 + wc * 64 + j * 16 + cl;
            float bb = bO[col];
            #pragma unroll
            for (int r = 0; r < 4; ++r) {
                int p = m0 + wr * 64 + i * 16 + g * 4 + r;
                out[(size_t)p * DM + col] = acc[i][j][r] + bb;
            }
        }
}

// ---------------------------------------------------------------------------
extern "C" void kernel_launch(void* const* d_in, const int* in_sizes, int n_in,
                              void* d_out, int out_size, void* d_ws, size_t ws_size,
                              hipStream_t stream) {
    const float* resid = (const float*)d_in[0];
    const float* WQ = (const float*)d_in[1];
    const float* WK = (const float*)d_in[2];
    const float* WV = (const float*)d_in[3];
    const float* WO = (const float*)d_in[4];
    const float* bQ = (const float*)d_in[5];
    const float* bK = (const float*)d_in[6];
    const float* bV = (const float*)d_in[7];
    const float* bO = (const float*)d_in[8];
    float* out = (float*)d_out;
    char* ws = (char*)d_ws;

    float2* rope = (float2*)(ws);                        // 1 MB
    u16* xn   = (u16*)(ws + (1ll  << 20));               // 8 MB
    u16* Wt   = (u16*)(ws + (9ll  << 20));               // 24 MB  [3][16][128][2048]
    u16* Wot  = (u16*)(ws + (33ll << 20));               // 8 MB   [2048][2048]
    u16* qkv  = (u16*)(ws + (41ll << 20));               // 24 MB  [q][k][vT]
    u16* z    = (u16*)(ws + (65ll << 20));               // 8 MB   [16][2048][128]
    // flash partials OVERLAY rope/xn/Wt (dead after gemm_qkv; rewritten next call)
    u16* pO   = (u16*)(ws);                              // 18.9 MB (1152 x 64 x 128 bf16)
    float2* ml = (float2*)(ws + (20ll << 20));           // 0.6 MB

    prep_kernel<<<SEQ + 4096, 256, 0, stream>>>(resid, WQ, WK, WV, WO, xn, rope, Wt, Wot);

    gemm_qkv<<<256, 512, 0, stream>>>(xn, Wt, bQ, bK, bV, rope, qkv);

    const u16* Qg = qkv;
    const u16* Kg = qkv + 1ll * NH * SEQ * DH;
    const u16* Vt = qkv + 2ll * NH * SEQ * DH;
    flash_kernel<<<dim3(NH, 80), 256, 0, stream>>>(Qg, Kg, Vt, z, pO, ml);
    merge_kernel<<<dim3(NH, 24), 256, 0, stream>>>(pO, ml, z);

    gemm_out<<<256, 256, 0, stream>>>(z, Wot, bO, out);
}